// Round 9
// baseline (15934.511 us; speedup 1.0000x reference)
//
#include <hip/hip_runtime.h>
#include <cstdint>

#define NB 1024
#define NS 128
#define NH 256

typedef unsigned short ushort_t;
typedef unsigned char uchar_t;

__device__ __forceinline__ void tf2x32(uint32_t k0, uint32_t k1, uint32_t x0, uint32_t x1,
                                       uint32_t &o0, uint32_t &o1) {
  const uint32_t ks2 = k0 ^ k1 ^ 0x1BD11BDAu;
#define TF_R(r) { x0 += x1; x1 = (x1 << (r)) | (x1 >> (32 - (r))); x1 ^= x0; }
  x0 += k0; x1 += k1;
  TF_R(13) TF_R(15) TF_R(26) TF_R(6)
  x0 += k1; x1 += ks2 + 1u;
  TF_R(17) TF_R(29) TF_R(16) TF_R(24)
  x0 += ks2; x1 += k0 + 2u;
  TF_R(13) TF_R(15) TF_R(26) TF_R(6)
  x0 += k0; x1 += k1 + 3u;
  TF_R(17) TF_R(29) TF_R(16) TF_R(24)
  x0 += k1; x1 += ks2 + 4u;
  TF_R(13) TF_R(15) TF_R(26) TF_R(6)
  x0 += ks2; x1 += k0 + 5u;
#undef TF_R
  o0 = x0; o1 = x1;
}

__device__ __forceinline__ float fast_tanh(float x) {
  float ax = fabsf(x);
  float e = __expf(2.0f * ax);
  float r = 1.0f - 2.0f / (e + 1.0f);
  return copysignf(r, x);
}

__device__ __forceinline__ float sigm(float x) { return 1.0f / (1.0f + expf(-x)); }

// ---- 3.5-byte key codec: keep fp32 bits [31:4] with RTN. Planes: hi16, lo8, nibble4 ----
__device__ __forceinline__ float4 key_load(const ushort_t* __restrict__ kh,
                                           const uchar_t* __restrict__ k8,
                                           const ushort_t* __restrict__ kn,
                                           size_t row, int h0) {
  ushort4 hv = *(const ushort4*)(kh + row * 256 + h0);
  uchar4 lv = *(const uchar4*)(k8 + row * 256 + h0);
  uint32_t nv = kn[row * 64 + (h0 >> 2)];
  float4 r;
  r.x = __uint_as_float(((uint32_t)hv.x << 16) | ((uint32_t)lv.x << 8) | ((nv & 0xFu) << 4));
  r.y = __uint_as_float(((uint32_t)hv.y << 16) | ((uint32_t)lv.y << 8) | (((nv >> 4) & 0xFu) << 4));
  r.z = __uint_as_float(((uint32_t)hv.z << 16) | ((uint32_t)lv.z << 8) | (((nv >> 8) & 0xFu) << 4));
  r.w = __uint_as_float(((uint32_t)hv.w << 16) | ((uint32_t)lv.w << 8) | (((nv >> 12) & 0xFu) << 4));
  return r;
}

// ---------------- prep: fold emb_W through input weights; threefry split keys ----------------
__global__ __launch_bounds__(256) void prep_kernel(
    const float* __restrict__ emb_W, const float* __restrict__ enc_W_ih,
    const float* __restrict__ dec_W_ih, const float* __restrict__ dec_start,
    float* __restrict__ F_enc, float* __restrict__ F_dec,
    float* __restrict__ d0proj, uint2* __restrict__ skeys) {
  int j = blockIdx.x * 256 + threadIdx.x;  // 0..1023
  const float* er = enc_W_ih + j * 256;
  const float* dr = dec_W_ih + j * 256;
  float fe0 = 0.f, fe1 = 0.f, fd0 = 0.f, fd1 = 0.f, dp = 0.f;
  for (int e = 0; e < 256; ++e) {
    float we0 = emb_W[e], we1 = emb_W[256 + e];
    float ev = er[e], dv = dr[e];
    fe0 = fmaf(we0, ev, fe0); fe1 = fmaf(we1, ev, fe1);
    fd0 = fmaf(we0, dv, fd0); fd1 = fmaf(we1, dv, fd1);
    dp = fmaf(dec_start[e], dv, dp);
  }
  F_enc[j] = fe0; F_enc[1024 + j] = fe1;
  F_dec[j] = fd0; F_dec[1024 + j] = fd1;
  d0proj[j] = dp;
  if (blockIdx.x == 0 && threadIdx.x < NS) {
    uint32_t o0, o1;
    tf2x32(0u, 42u, 0u, (uint32_t)threadIdx.x, o0, o1);
    skeys[threadIdx.x] = make_uint2(o0, o1);
  }
}

// ---------------- transpose all weight matrices (k-major for coalesced matvec) ----------------
__global__ __launch_bounds__(1024) void transpose_all(
    const float* __restrict__ encW, const float* __restrict__ decW,
    const float* __restrict__ gWk, const float* __restrict__ pWk,
    const float* __restrict__ gWq, const float* __restrict__ pWq,
    float* __restrict__ encT, float* __restrict__ decT, float* __restrict__ WkT,
    float* __restrict__ gWT, float* __restrict__ pWT) {
  int k = blockIdx.x;        // 0..255
  int j = threadIdx.x;       // 0..1023
  encT[k * 1024 + j] = encW[j * 256 + k];
  decT[k * 1024 + j] = decW[j * 256 + k];
  if (j < 512) WkT[k * 512 + j] = (j < 256) ? gWk[j * 256 + k] : pWk[(j - 256) * 256 + k];
  if (j < 256) {
    gWT[k * 256 + j] = gWq[j * 256 + k];
    pWT[k * 256 + j] = pWq[j * 256 + k];
  }
}

__global__ void diag_fill(float* out, float v, int n) {
  int i = blockIdx.x * blockDim.x + threadIdx.x;
  if (i < n) out[i] = v;
}

// ---------------- the whole network: one plain kernel, 4 batch rows / block ----------------
__global__ __launch_bounds__(1024) void net_kernel(
    const float* __restrict__ x,
    const float* __restrict__ encT, const float* __restrict__ decT,
    const float* __restrict__ enc_b_ih, const float* __restrict__ enc_b_hh,
    const float* __restrict__ dec_b_ih, const float* __restrict__ dec_b_hh,
    const float* __restrict__ F_enc, const float* __restrict__ F_dec,
    const float* __restrict__ d0proj,
    const float* __restrict__ WkT, const float* __restrict__ gkb, const float* __restrict__ pkb,
    const float* __restrict__ gWT, const float* __restrict__ pWT,
    const float* __restrict__ gqb, const float* __restrict__ pqb,
    const float* __restrict__ gvw, const float* __restrict__ gvb,
    const float* __restrict__ pvw, const float* __restrict__ pvb,
    ushort_t* __restrict__ gkh, uchar_t* __restrict__ gk8, ushort_t* __restrict__ gkn,
    ushort_t* __restrict__ pkh, uchar_t* __restrict__ pk8, ushort_t* __restrict__ pkn,
    const uint2* __restrict__ skeys, float* __restrict__ out) {
  __shared__ float h4[256][4];        // h4[k][r]
  __shared__ float gx[1024][4];       // gate exchange [j][r]
  __shared__ float xs[1024];          // x preload [r][256]
  __shared__ float qs[4][256], vsm[4][256], qq[4][256];
  __shared__ float part[4][4][256];   // qproj split-k partials AND glimpse per-wave partials
  __shared__ float wl[4][4];
  __shared__ float lgs[4][NS], sv[4][NS];
  __shared__ int msk[4][NS];
  __shared__ int chs[4];

  const int tid = threadIdx.x;
  const int r_own = tid >> 8, e_own = tid & 255;
  const int bb = blockIdx.x * 4;

  // preloads + init
  xs[tid] = x[(size_t)(bb + r_own) * 256 + e_own];
  if (tid < 512) ((int*)msk)[tid] = 0;
  ((float*)h4)[tid] = 0.0f;
  const float bse = enc_b_ih[tid] + enc_b_hh[tid];
  const float fae = F_enc[tid], fbe = F_enc[1024 + tid];
  const float bsd = dec_b_ih[tid] + dec_b_hh[tid];
  const float fad = F_dec[tid], fbd = F_dec[1024 + tid];
  const float d0p = d0proj[tid];
  float h_own = 0.0f, c_own = 0.0f;
  const int lane_blk = tid & 63;
  __syncthreads();

  // keys projection lambda: all 1024 threads, 2 columns each, for step kt (reads h4)
  auto do_keys = [&](int kt) {
    const int r = tid >> 8;            // row 0..3
    const int cp = tid & 255;          // column pair 0..255
    const int j0 = cp * 2;             // 0..510 even
    float2 ka = make_float2(0.f, 0.f);
    const float* wk = WkT + j0;
#pragma unroll 8
    for (int k = 0; k < 256; ++k) {
      float hk = h4[k][r];
      float2 w2 = *(const float2*)(wk + (size_t)k * 512);
      ka.x = fmaf(hk, w2.x, ka.x);
      ka.y = fmaf(hk, w2.y, ka.y);
    }
    const bool isp = (j0 >= 256);
    const int n = isp ? (j0 - 256) : j0;
    float2 b2 = *(const float2*)((isp ? pkb : gkb) + n);
    ka.x += b2.x; ka.y += b2.y;
    size_t rowg = (size_t)(bb + r) * NS + kt;
    uint32_t a = __float_as_uint(ka.x) + 8u;
    uint32_t b = __float_as_uint(ka.y) + 8u;
    ushort_t* kh = isp ? pkh : gkh;
    uchar_t* k8 = isp ? pk8 : gk8;
    ushort_t* kn = isp ? pkn : gkn;
    *(ushort2*)(kh + rowg * 256 + n) = make_ushort2((ushort_t)(a >> 16), (ushort_t)(b >> 16));
    *(uchar2*)(k8 + rowg * 256 + n) = make_uchar2((uchar_t)(a >> 8), (uchar_t)(b >> 8));
    uint32_t nib2 = ((a >> 4) & 0xFu) | (((b >> 4) & 0xFu) << 4);
    uint32_t nOther = __shfl_down((int)nib2, 1);
    if ((lane_blk & 1) == 0)
      kn[rowg * 64 + (n >> 2)] = (ushort_t)(nib2 | (nOther << 8));
  };

  // ================= encoder =================
  for (int t = 0; t < NS; ++t) {
    // region A: matvec(t) [reads h4 = h(t-1)]  ||  keys(t-1) [reads h4 = h(t-1)]
    float4 acc = make_float4(0.f, 0.f, 0.f, 0.f);
    {
      const float* wt = encT + tid;
      const float4* hv4 = (const float4*)h4;
#pragma unroll 8
      for (int k = 0; k < 256; ++k) {
        float4 hv = hv4[k];
        float w = wt[(size_t)k * 1024];
        acc.x = fmaf(w, hv.x, acc.x);
        acc.y = fmaf(w, hv.y, acc.y);
        acc.z = fmaf(w, hv.z, acc.z);
        acc.w = fmaf(w, hv.w, acc.w);
      }
    }
    if (t > 0) do_keys(t - 1);
    {
      float4 v;
      v.x = acc.x + bse + xs[2 * t] * fae + xs[2 * t + 1] * fbe;
      v.y = acc.y + bse + xs[256 + 2 * t] * fae + xs[256 + 2 * t + 1] * fbe;
      v.z = acc.z + bse + xs[512 + 2 * t] * fae + xs[512 + 2 * t + 1] * fbe;
      v.w = acc.w + bse + xs[768 + 2 * t] * fae + xs[768 + 2 * t + 1] * fbe;
      *(float4*)gx[tid] = v;
    }
    __syncthreads();
    {
      float gi = gx[e_own][r_own], gf = gx[e_own + 256][r_own];
      float gg = gx[e_own + 512][r_own], go = gx[e_own + 768][r_own];
      c_own = sigm(gf) * c_own + sigm(gi) * tanhf(gg);
      h_own = sigm(go) * tanhf(c_own);
      h4[e_own][r_own] = h_own;
    }
    __syncthreads();
  }

  // ================= decoder =================
  for (int t = 0; t < NS; ++t) {
    // region A: matvec(t) || (t==0: keys(127))
    float4 acc = make_float4(0.f, 0.f, 0.f, 0.f);
    {
      const float* wt = decT + tid;
      const float4* hv4 = (const float4*)h4;
#pragma unroll 8
      for (int k = 0; k < 256; ++k) {
        float4 hv = hv4[k];
        float w = wt[(size_t)k * 1024];
        acc.x = fmaf(w, hv.x, acc.x);
        acc.y = fmaf(w, hv.y, acc.y);
        acc.z = fmaf(w, hv.z, acc.z);
        acc.w = fmaf(w, hv.w, acc.w);
      }
    }
    if (t == 0) do_keys(NS - 1);
    {
      float4 v;
      if (t == 0) {
        v.x = acc.x + bsd + d0p;
        v.y = acc.y + bsd + d0p;
        v.z = acc.z + bsd + d0p;
        v.w = acc.w + bsd + d0p;
      } else {
        int c0 = chs[0], c1 = chs[1], c2 = chs[2], c3 = chs[3];
        v.x = acc.x + bsd + xs[2 * c0] * fad + xs[2 * c0 + 1] * fbd;
        v.y = acc.y + bsd + xs[256 + 2 * c1] * fad + xs[256 + 2 * c1 + 1] * fbd;
        v.z = acc.z + bsd + xs[512 + 2 * c2] * fad + xs[512 + 2 * c2 + 1] * fbd;
        v.w = acc.w + bsd + xs[768 + 2 * c3] * fad + xs[768 + 2 * c3 + 1] * fbd;
      }
      *(float4*)gx[tid] = v;
    }
    __syncthreads();
    {
      float gi = gx[e_own][r_own], gf = gx[e_own + 256][r_own];
      float gg = gx[e_own + 512][r_own], go = gx[e_own + 768][r_own];
      c_own = sigm(gf) * c_own + sigm(gi) * tanhf(gg);
      h_own = sigm(go) * tanhf(c_own);
      h4[e_own][r_own] = h_own;
    }
    __syncthreads();

    // ---- fused attention + sample ----
    const int grp = tid >> 8;
    const int gt = tid & 255;
    const int b = bb + grp;
    const int wv = gt >> 6, lane = gt & 63;
    const int h0 = lane * 4;
    const int quad4 = (gt & 63) * 4;   // split-k output base
    const int kq = gt >> 6;            // split-k k-quarter

    // phase 1 partials: qg = g_Wq . h (split-k-4, float4 weights)
    {
      float4 a = make_float4(0.f, 0.f, 0.f, 0.f);
      const float* wc = gWT + quad4;
      const int kbeg = kq * 64;
#pragma unroll 8
      for (int k = kbeg; k < kbeg + 64; ++k) {
        float hk = h4[k][grp];
        float4 w4 = *(const float4*)(wc + (size_t)k * 256);
        a.x = fmaf(hk, w4.x, a.x);
        a.y = fmaf(hk, w4.y, a.y);
        a.z = fmaf(hk, w4.z, a.z);
        a.w = fmaf(hk, w4.w, a.w);
      }
      *(float4*)&part[grp][kq][quad4] = a;
    }
    __syncthreads();
    // phase 1 combine + v-load + gumbel precompute
    {
      qs[grp][gt] = gqb[gt] + part[grp][0][gt] + part[grp][1][gt] +
                    part[grp][2][gt] + part[grp][3][gt];
      vsm[grp][gt] = gvw[gt];
      if (gt < NS) {
        uint32_t i = (uint32_t)(b * NS + gt);
        uint2 sk = skeys[t];
        uint32_t o0, o1;
        tf2x32(sk.x, sk.y, 0u, i, o0, o1);
        uint32_t bits = o0 ^ o1;
        float u = __uint_as_float((bits >> 9) | 0x3f800000u) - 1.0f;
        u = u + 1.17549435e-38f;
        u = fmaxf(u, 1.17549435e-38f);
        sv[grp][gt] = -logf(-logf(u));   // gumbel noise only
      }
    }
    __syncthreads();

    // phase 2: glimpse attention, bounded logits -> no max tracking
    {
      const float vbias = gvb[0];
      float q0 = qs[grp][h0], q1 = qs[grp][h0 + 1], q2 = qs[grp][h0 + 2], q3 = qs[grp][h0 + 3];
      float v0 = vsm[grp][h0], v1 = vsm[grp][h0 + 1], v2 = vsm[grp][h0 + 2], v3 = vsm[grp][h0 + 3];
      float l = 0.f;
      float4 acc2 = make_float4(0.f, 0.f, 0.f, 0.f);
#pragma unroll 2
      for (int si = 0; si < 32; ++si) {
        int s = wv * 32 + si;
        if (msk[grp][s]) continue;
        size_t row = (size_t)b * NS + s;
        float4 kv = key_load(gkh, gk8, gkn, row, h0);
        float p = fast_tanh(q0 + kv.x) * v0 + fast_tanh(q1 + kv.y) * v1 +
                  fast_tanh(q2 + kv.z) * v2 + fast_tanh(q3 + kv.w) * v3;
#pragma unroll
        for (int off = 32; off; off >>= 1) p += __shfl_xor(p, off);
        float lg = 10.0f * tanhf(p + vbias);
        float pe = expf(lg);             // lg in [-10,10]: safe
        acc2.x = fmaf(pe, kv.x, acc2.x);
        acc2.y = fmaf(pe, kv.y, acc2.y);
        acc2.z = fmaf(pe, kv.z, acc2.z);
        acc2.w = fmaf(pe, kv.w, acc2.w);
        l += pe;
      }
      *(float4*)&part[grp][wv][h0] = acc2;
      if (lane == 0) wl[grp][wv] = l;
    }
    __syncthreads();
    // phase 2 combine
    {
      float den = wl[grp][0] + wl[grp][1] + wl[grp][2] + wl[grp][3];
      float num = part[grp][0][gt] + part[grp][1][gt] + part[grp][2][gt] + part[grp][3][gt];
      qq[grp][gt] = num / den;
      vsm[grp][gt] = pvw[gt];
    }
    __syncthreads();

    // phase 3 partials: qp = p_Wq . query (split-k-4)
    {
      float4 a = make_float4(0.f, 0.f, 0.f, 0.f);
      const float* wc = pWT + quad4;
      const int kbeg = kq * 64;
#pragma unroll 8
      for (int k = kbeg; k < kbeg + 64; ++k) {
        float hk = qq[grp][k];
        float4 w4 = *(const float4*)(wc + (size_t)k * 256);
        a.x = fmaf(hk, w4.x, a.x);
        a.y = fmaf(hk, w4.y, a.y);
        a.z = fmaf(hk, w4.z, a.z);
        a.w = fmaf(hk, w4.w, a.w);
      }
      *(float4*)&part[grp][kq][quad4] = a;
    }
    __syncthreads();
    {
      qs[grp][gt] = pqb[gt] + part[grp][0][gt] + part[grp][1][gt] +
                    part[grp][2][gt] + part[grp][3][gt];
    }
    __syncthreads();

    // phase 4: pointer logits (mask-skip)
    {
      const float vbias = pvb[0];
      float q0 = qs[grp][h0], q1 = qs[grp][h0 + 1], q2 = qs[grp][h0 + 2], q3 = qs[grp][h0 + 3];
      float v0 = vsm[grp][h0], v1 = vsm[grp][h0 + 1], v2 = vsm[grp][h0 + 2], v3 = vsm[grp][h0 + 3];
#pragma unroll 2
      for (int si = 0; si < 32; ++si) {
        int s = wv * 32 + si;
        if (msk[grp][s]) {
          if (lane == 0) lgs[grp][s] = -100000.0f;
          continue;
        }
        size_t row = (size_t)b * NS + s;
        float4 kv = key_load(pkh, pk8, pkn, row, h0);
        float p = fast_tanh(q0 + kv.x) * v0 + fast_tanh(q1 + kv.y) * v1 +
                  fast_tanh(q2 + kv.z) * v2 + fast_tanh(q3 + kv.w) * v3;
#pragma unroll
        for (int off = 32; off; off >>= 1) p += __shfl_down(p, off);
        if (lane == 0) lgs[grp][s] = 10.0f * tanhf(p + vbias);
      }
    }
    __syncthreads();

    // fused LSE + gumbel argmax + writeout (wave 0 of each group)
    if (wv == 0) {
      float a0 = lgs[grp][lane], a1 = lgs[grp][lane + 64];
      float es = expf(a0) + expf(a1);            // exp(-1e5) flushes to 0
      float b0 = a0 + sv[grp][lane], b1 = a1 + sv[grp][lane + 64];
      float bv; int bi;
      if (b1 > b0) { bv = b1; bi = lane + 64; } else { bv = b0; bi = lane; }
#pragma unroll
      for (int off = 32; off; off >>= 1) {
        es += __shfl_xor(es, off);
        float ov = __shfl_down(bv, off);
        int oi = __shfl_down(bi, off);
        if (ov > bv) { bv = ov; bi = oi; }
      }
      if (lane == 0) {
        int cs = bi;
        out[(size_t)b * NS + t] = lgs[grp][cs] - logf(es);
        out[(size_t)NB * NS + (size_t)b * NS + t] = (float)cs;
        msk[grp][cs] = 1;
        chs[grp] = cs;
      }
    }
    __syncthreads();
  }
}

extern "C" void kernel_launch(void* const* d_in, const int* in_sizes, int n_in,
                              void* d_out, int out_size, void* d_ws, size_t ws_size,
                              hipStream_t stream) {
  const float* x        = (const float*)d_in[0];
  const float* emb_W    = (const float*)d_in[1];
  const float* enc_W_ih = (const float*)d_in[2];
  const float* enc_W_hh = (const float*)d_in[3];
  const float* enc_b_ih = (const float*)d_in[4];
  const float* enc_b_hh = (const float*)d_in[5];
  const float* dec_W_ih = (const float*)d_in[6];
  const float* dec_W_hh = (const float*)d_in[7];
  const float* dec_b_ih = (const float*)d_in[8];
  const float* dec_b_hh = (const float*)d_in[9];
  const float* g_Wq_w = (const float*)d_in[10];
  const float* g_Wq_b = (const float*)d_in[11];
  const float* g_Wk_w = (const float*)d_in[12];
  const float* g_Wk_b = (const float*)d_in[13];
  const float* g_v_w  = (const float*)d_in[14];
  const float* g_v_b  = (const float*)d_in[15];
  const float* p_Wq_w = (const float*)d_in[16];
  const float* p_Wq_b = (const float*)d_in[17];
  const float* p_Wk_w = (const float*)d_in[18];
  const float* p_Wk_b = (const float*)d_in[19];
  const float* p_v_w  = (const float*)d_in[20];
  const float* p_v_b  = (const float*)d_in[21];
  const float* dec_start = (const float*)d_in[22];
  (void)in_sizes; (void)n_in;

  const size_t KELEM = (size_t)NB * NS * NH;   // 33.55M per head
  char* w = (char*)d_ws;
  size_t off = 0;
  auto alloc = [&](size_t bytes) -> void* {
    void* p = w + off;
    off += (bytes + 255) & ~(size_t)255;
    return p;
  };
  // quantized keys: 3.5 B/elem, both heads = 224 MiB total
  ushort_t* gkh = (ushort_t*)alloc(KELEM * 2);
  uchar_t*  gk8 = (uchar_t*)alloc(KELEM);
  ushort_t* gkn = (ushort_t*)alloc(KELEM / 2);
  ushort_t* pkh = (ushort_t*)alloc(KELEM * 2);
  uchar_t*  pk8 = (uchar_t*)alloc(KELEM);
  ushort_t* pkn = (ushort_t*)alloc(KELEM / 2);

  float* encT   = (float*)alloc(1024 * 256 * 4);
  float* decT   = (float*)alloc(1024 * 256 * 4);
  float* WkT    = (float*)alloc(512 * 256 * 4);
  float* gWT    = (float*)alloc(256 * 256 * 4);
  float* pWT    = (float*)alloc(256 * 256 * 4);
  float* F_enc  = (float*)alloc(2048 * 4);
  float* F_dec  = (float*)alloc(2048 * 4);
  float* d0proj = (float*)alloc(1024 * 4);
  uint2* skeys  = (uint2*)alloc(NS * 8);

  if (off > ws_size) {
    diag_fill<<<(out_size + 255) / 256, 256, 0, stream>>>((float*)d_out, (float)ws_size, out_size);
    return;
  }

  prep_kernel<<<4, 256, 0, stream>>>(emb_W, enc_W_ih, dec_W_ih, dec_start,
                                     F_enc, F_dec, d0proj, skeys);
  transpose_all<<<256, 1024, 0, stream>>>(enc_W_hh, dec_W_hh, g_Wk_w, p_Wk_w,
                                          g_Wq_w, p_Wq_w, encT, decT, WkT, gWT, pWT);
  net_kernel<<<NB / 4, 1024, 0, stream>>>(
      x, encT, decT, enc_b_ih, enc_b_hh, dec_b_ih, dec_b_hh,
      F_enc, F_dec, d0proj, WkT, g_Wk_b, p_Wk_b,
      gWT, pWT, g_Wq_b, p_Wq_b, g_v_w, g_v_b, p_v_w, p_v_b,
      gkh, gk8, gkn, pkh, pk8, pkn, skeys, (float*)d_out);
}